// Round 9
// baseline (405.596 us; speedup 1.0000x reference)
//
#include <hip/hip_runtime.h>
#include <math.h>

// ---------------------------------------------------------------------------
// GCN-VAE fused pipeline for MI355X.
// R15: structural merges on top of verified R14 (393.8us).
//  (1) agg64#2 (Q = A*P) fused INTO matmul_out: each block gathers its 64
//      Q-rows directly into ldsX as fp32 (skips Q's bf16 round-trip through
//      HBM: one fewer kernel, one fewer quantization, -13 MB streaming).
//  (2) scan_bases merged into build_kernel: every block redundantly scans
//      the 256 bucket totals in LDS (parallel ~2us) instead of a 1-block
//      kernel serializing the whole GPU.
// Aggs are at their measured structural floor (MSHR x latency ~3 TB/s fill,
// FETCH pinned at 165 MB): R9/R10/R13 MLP ladder converged 65->60us.
// CSR build / aggs / matmul<128> = verified R14, untouched.
// ---------------------------------------------------------------------------

__device__ inline float bf2f_lo(unsigned int v) {
    return __uint_as_float(v << 16);
}
__device__ inline float bf2f_hi(unsigned int v) {
    return __uint_as_float(v & 0xFFFF0000u);
}
__device__ inline unsigned short f2bf(float f) {
    unsigned int u = __float_as_uint(f);
    return (unsigned short)((u + 0x7FFFu + ((u >> 16) & 1u)) >> 16);
}
__device__ inline unsigned int packbf(float a, float b) {
    return (unsigned int)f2bf(a) | ((unsigned int)f2bf(b) << 16);
}
__device__ inline unsigned int get_xcd() {
    unsigned int x;
    asm volatile("s_getreg_b32 %0, hwreg(HW_REG_XCC_ID)" : "=s"(x));
    return x & 7u;
}

__global__ void zero_kernel(int* __restrict__ p, int n) {
    int i = blockIdx.x * blockDim.x + threadIdx.x;
    if (i < n) p[i] = 0;
}

// Pass 1: bucket edges (+self-loops) by dst>>8 into per-(bucket,XCD) slices.
__global__ __launch_bounds__(256) void bucketize_kernel(
    const int* __restrict__ src, const int* __restrict__ dst, int E, int N,
    int capS, uint2* __restrict__ pairs, int* __restrict__ gcnt) {
    __shared__ int lcnt[256];
    __shared__ int lbase[256];
    int tid = threadIdx.x;
    int total = E + N;
    int base = blockIdx.x * 4096;
    unsigned int x = get_xcd();
    lcnt[tid] = 0;
    __syncthreads();
    int d[16], s[16], rk[16];
#pragma unroll
    for (int j = 0; j < 16; j++) {
        int idx = base + j * 256 + tid;
        d[j] = -1;
        if (idx < total) {
            if (idx < E) { d[j] = dst[idx]; s[j] = src[idx]; }
            else         { d[j] = idx - E; s[j] = d[j]; }
            rk[j] = atomicAdd(&lcnt[d[j] >> 8], 1);
        }
    }
    __syncthreads();
    if (lcnt[tid] > 0) lbase[tid] = atomicAdd(&gcnt[tid * 8 + (int)x],
                                              lcnt[tid]);
    __syncthreads();
#pragma unroll
    for (int j = 0; j < 16; j++) {
        if (d[j] >= 0) {
            int b = d[j] >> 8;
            int pos = lbase[b] + rk[j];
            if (pos < capS)
                pairs[(size_t)(b * 8 + (int)x) * capS + pos] =
                    make_uint2((unsigned)d[j], (unsigned)s[j]);
        }
    }
}

// Pass 2 (merged scan + sort): one block per bucket. Each block redundantly
// computes the global bucket-total scan from gcnt in LDS (replaces the old
// single-block scan_bases kernel), then LDS counting sort by dst&255 and
// fully coalesced writes of offs/dinv/esrc. Block 0 writes offs[N].
__global__ __launch_bounds__(256) void build_kernel(
    const uint2* __restrict__ pairs, const int* __restrict__ gcnt, int capS,
    int N, int* __restrict__ offs, float* __restrict__ dinv,
    int* __restrict__ esrc) {
    __shared__ int gtot[256];
    __shared__ int cnt[256];
    __shared__ int loff[256];
    __shared__ int cur[256];
    __shared__ int S[10240];
    int b = blockIdx.x;
    int tid = threadIdx.x;

    // global bucket scan (replicated per block)
    int tb = 0;
#pragma unroll
    for (int x = 0; x < 8; x++) {
        int v = gcnt[tid * 8 + x];
        if (v > capS) v = capS;
        tb += v;
    }
    gtot[tid] = tb;
    cnt[tid] = 0;
    __syncthreads();
    for (int off = 1; off < 256; off <<= 1) {
        int u = (tid >= off) ? gtot[tid - off] : 0;
        __syncthreads();
        gtot[tid] += u;
        __syncthreads();
    }
    if (b == 0 && tid == 255) offs[N] = gtot[255];
    int base = (b == 0) ? 0 : gtot[b - 1];

    int szx[8];
#pragma unroll
    for (int x = 0; x < 8; x++) {
        int v = gcnt[b * 8 + x];
        if (v > capS) v = capS;
        szx[x] = v;
    }
#pragma unroll
    for (int x = 0; x < 8; x++) {
        const uint2* bp = pairs + (size_t)(b * 8 + x) * capS;
        for (int i = tid; i < szx[x]; i += 256)
            atomicAdd(&cnt[bp[i].x & 255u], 1);
    }
    __syncthreads();
    int c = cnt[tid];
    loff[tid] = c;
    __syncthreads();
    for (int off = 1; off < 256; off <<= 1) {
        int u = (tid >= off) ? loff[tid - off] : 0;
        __syncthreads();
        loff[tid] += u;
        __syncthreads();
    }
    int excl = loff[tid] - c;
    cur[tid] = excl;
    int total = loff[255];
    int d0 = b << 8;
    if (d0 + tid < N) {
        offs[d0 + tid] = base + excl;
        dinv[d0 + tid] = rsqrtf((float)c);   // c >= 1 (self-loop)
    }
    __syncthreads();
#pragma unroll
    for (int x = 0; x < 8; x++) {
        const uint2* bp = pairs + (size_t)(b * 8 + x) * capS;
        for (int i = tid; i < szx[x]; i += 256) {
            uint2 p = bp[i];
            int pos = atomicAdd(&cur[p.x & 255u], 1);
            if (pos < 10240) S[pos] = (int)p.y;
        }
    }
    __syncthreads();
    if (total > 10240) total = 10240;
    for (int j = tid; j < total; j += 256) esrc[base + j] = S[j];
}

// Collapse weights on-device (tiny):
//  Wc[k][2j]=sum_m We[k][m]*Wm[m][j], Wc[k][2j+1]=sum_m We[k][m]*Wl[m][j]
//  Wd[k][c]=sum_m Wd1[k][m]*Wd2[m][c]
//  bc[2j]=be@Wm, bc[2j+1]=be@Wl; b2c = interleave(bm,bl); bd12 = bd1@Wd2
__global__ __launch_bounds__(256) void wcomb_kernel(
    const float* __restrict__ We, const float* __restrict__ be,
    const float* __restrict__ Wm, const float* __restrict__ bm,
    const float* __restrict__ Wl, const float* __restrict__ bl,
    const float* __restrict__ Wd1, const float* __restrict__ bd1,
    const float* __restrict__ Wd2, float* __restrict__ Wc,
    float* __restrict__ bc, float* __restrict__ b2c, float* __restrict__ Wd,
    float* __restrict__ bd12) {
    int i = blockIdx.x * 256 + threadIdx.x;
    if (i < 16384) {                          // Wc (128x128 interleaved)
        int k = i >> 7, c = i & 127, j = c >> 1;
        const float* Wx = (c & 1) ? Wl : Wm;
        float s = 0.f;
        for (int m = 0; m < 128; m++) s += We[k * 128 + m] * Wx[m * 64 + j];
        Wc[k * 128 + c] = s;
    } else if (i < 16384 + 8192) {            // Wd (64x128)
        int t = i - 16384;
        int k = t >> 7, c = t & 127;
        float s = 0.f;
        for (int m = 0; m < 128; m++) s += Wd1[k * 128 + m] * Wd2[m * 128 + c];
        Wd[k * 128 + c] = s;
    } else if (i < 16384 + 8192 + 128) {      // bc
        int c = i - (16384 + 8192), j = c >> 1;
        const float* Wx = (c & 1) ? Wl : Wm;
        float s = 0.f;
        for (int m = 0; m < 128; m++) s += be[m] * Wx[m * 64 + j];
        bc[c] = s;
    } else if (i < 16384 + 8192 + 256) {      // b2c
        int c = i - (16384 + 8192 + 128);
        b2c[c] = (c & 1) ? bl[c >> 1] : bm[c >> 1];
    } else if (i < 16384 + 8192 + 384) {      // bd12
        int c = i - (16384 + 8192 + 256);
        float s = 0.f;
        for (int m = 0; m < 128; m++) s += bd1[m] * Wd2[m * 128 + c];
        bd12[c] = s;
    }
}

// Tiled matmul: out[N,128] = X[N,K] @ W[K,128], bf16 out, dinv row prescale.
// Both column halves computed by one block (X staged to LDS once).
template <int K, bool XBF, bool SCALE>
__global__ __launch_bounds__(256, 4) void matmul_kernel(
    const void* __restrict__ Xv, const float* __restrict__ W,
    const float* __restrict__ dinv, unsigned short* __restrict__ out, int N) {
    const int M = 128;
    const int KP = K + 4;
    __shared__ float ldsW[K][64];
    __shared__ float ldsX[64][KP];
    int tid = threadIdx.x;
    int row0 = blockIdx.x * 64;

    int maxr = N - row0; if (maxr > 64) maxr = 64;
    if (XBF) {
        const unsigned short* X = (const unsigned short*)Xv;
        for (int i = tid; i < maxr * (K / 8); i += 256) {
            int r = i / (K / 8), c8 = i % (K / 8);
            uint4 u = *(const uint4*)&X[(size_t)(row0 + r) * K + c8 * 8];
            float* dp = &ldsX[r][c8 * 8];
            dp[0] = bf2f_lo(u.x); dp[1] = bf2f_hi(u.x);
            dp[2] = bf2f_lo(u.y); dp[3] = bf2f_hi(u.y);
            dp[4] = bf2f_lo(u.z); dp[5] = bf2f_hi(u.z);
            dp[6] = bf2f_lo(u.w); dp[7] = bf2f_hi(u.w);
        }
    } else {
        const float* X = (const float*)Xv;
        for (int i = tid; i < maxr * (K / 4); i += 256) {
            int r = i / (K / 4), k4 = i % (K / 4);
            *(float4*)&ldsX[r][k4 * 4] =
                *(const float4*)&X[(size_t)(row0 + r) * K + k4 * 4];
        }
    }

    int cg = tid & 15, rg = tid >> 4;
    int rbase = rg * 4, cbase = cg * 4;

    for (int half = 0; half < 2; half++) {
        int col0 = half * 64;
        if (half) __syncthreads();   // protect ldsW reuse vs prior reads
        for (int i = tid; i < K * 16; i += 256) {
            int k = i >> 4, j4 = i & 15;
            ((float4*)&ldsW[k][0])[j4] =
                *(const float4*)&W[(size_t)k * M + col0 + j4 * 4];
        }
        __syncthreads();

        float acc[4][4] = {};
#pragma unroll 2
        for (int k = 0; k < K; k += 4) {
            float4 xv[4];
#pragma unroll
            for (int r = 0; r < 4; r++)
                xv[r] = *(const float4*)&ldsX[rbase + r][k];
            const float* xp = (const float*)xv;
#pragma unroll
            for (int kk = 0; kk < 4; kk++) {
                float4 wv = *(const float4*)&ldsW[k + kk][cbase];
#pragma unroll
                for (int r = 0; r < 4; r++) {
                    float xs = xp[r * 4 + kk];
                    acc[r][0] += xs * wv.x;
                    acc[r][1] += xs * wv.y;
                    acc[r][2] += xs * wv.z;
                    acc[r][3] += xs * wv.w;
                }
            }
        }
#pragma unroll
        for (int r = 0; r < 4; r++) {
            int row = row0 + rbase + r;
            if (row < N) {
                float sc = SCALE ? dinv[row] : 1.0f;
                ushort4 o;
                o.x = f2bf(acc[r][0] * sc); o.y = f2bf(acc[r][1] * sc);
                o.z = f2bf(acc[r][2] * sc); o.w = f2bf(acc[r][3] * sc);
                *(ushort4*)&out[(size_t)row * M + col0 + cbase] = o;
            }
        }
    }
}

// R15 fused decoder tail: Q = A*P gathered DIRECTLY into ldsX (fp32), then
// out[N,128] = Q@Wd + r[row]*b1[col] + b2[col] (fp32 out).
// Phase 1: wave w computes Q rows w*16..w*16+15 of this block's 64 dsts via
// the verified agg64 quarter-wave loop (p=lane>>4 edge parity, c=lane&15
// owns cols 4c..4c+3); lanes<16 store float4 to ldsX (no bf16 round-trip).
// Phase 2: verified matmul_out half-loop.
__global__ __launch_bounds__(256, 4) void fused_out_kernel(
    const unsigned short* __restrict__ P, const int* __restrict__ offsets,
    const int* __restrict__ esrc, const float* __restrict__ dinv,
    const float* __restrict__ W, const float* __restrict__ rvec,
    const float* __restrict__ b1, const float* __restrict__ b2,
    float* __restrict__ out, int N) {
    const int K = 64, M = 128;
    const int KP = K + 4;
    __shared__ float ldsW[K][64];
    __shared__ float ldsX[64][KP];
    int tid = threadIdx.x;
    int row0 = blockIdx.x * 64;
    int lane = tid & 63;
    int w = tid >> 6;
    int p = lane >> 4;
    int c = lane & 15;
    const uint2* Pu2 = (const uint2*)P;   // P row = 16 uint2 (128 B)

    // ---- Phase 1: gather Q rows into ldsX ----
    for (int i = 0; i < 16; i++) {
        int lr = w * 16 + i;
        int d = row0 + lr;
        if (d >= N) break;               // uniform per wave (d grows with i)
        int beg = offsets[d], end = offsets[d + 1];
        float a0 = 0.f, a1 = 0.f, a2 = 0.f, a3 = 0.f;
        int e = beg;
        for (; e + 16 <= end; e += 16) {
            int ss[4];
#pragma unroll
            for (int j = 0; j < 4; j++) ss[j] = esrc[e + 4 * j + p];
            uint2 vv[4];
#pragma unroll
            for (int j = 0; j < 4; j++) vv[j] = Pu2[(size_t)ss[j] * 16 + c];
#pragma unroll
            for (int j = 0; j < 4; j++) {
                a0 += bf2f_lo(vv[j].x); a1 += bf2f_hi(vv[j].x);
                a2 += bf2f_lo(vv[j].y); a3 += bf2f_hi(vv[j].y);
            }
        }
        for (; e + 4 <= end; e += 4) {
            int s = esrc[e + p];
            uint2 v = Pu2[(size_t)s * 16 + c];
            a0 += bf2f_lo(v.x); a1 += bf2f_hi(v.x);
            a2 += bf2f_lo(v.y); a3 += bf2f_hi(v.y);
        }
        int rem = end - e;
        if (p < rem) {
            int s = esrc[e + p];
            uint2 v = Pu2[(size_t)s * 16 + c];
            a0 += bf2f_lo(v.x); a1 += bf2f_hi(v.x);
            a2 += bf2f_lo(v.y); a3 += bf2f_hi(v.y);
        }
        a0 += __shfl_xor(a0, 16); a1 += __shfl_xor(a1, 16);
        a2 += __shfl_xor(a2, 16); a3 += __shfl_xor(a3, 16);
        a0 += __shfl_xor(a0, 32); a1 += __shfl_xor(a1, 32);
        a2 += __shfl_xor(a2, 32); a3 += __shfl_xor(a3, 32);
        if (lane < 16) {
            float dd = dinv[d];
            *(float4*)&ldsX[lr][c * 4] =
                make_float4(a0 * dd, a1 * dd, a2 * dd, a3 * dd);
        }
    }
    __syncthreads();

    // ---- Phase 2: matmul half-loop (verified R14 matmul_out body) ----
    int cg = tid & 15, rg = tid >> 4;
    int rbase = rg * 4, cbase = cg * 4;

    for (int half = 0; half < 2; half++) {
        int col0 = half * 64;
        if (half) __syncthreads();
        for (int i = tid; i < K * 16; i += 256) {
            int k = i >> 4, j4 = i & 15;
            ((float4*)&ldsW[k][0])[j4] =
                *(const float4*)&W[(size_t)k * M + col0 + j4 * 4];
        }
        __syncthreads();

        float acc[4][4] = {};
#pragma unroll 2
        for (int k = 0; k < K; k += 4) {
            float4 xv[4];
#pragma unroll
            for (int r = 0; r < 4; r++)
                xv[r] = *(const float4*)&ldsX[rbase + r][k];
            const float* xp = (const float*)xv;
#pragma unroll
            for (int kk = 0; kk < 4; kk++) {
                float4 wv = *(const float4*)&ldsW[k + kk][cbase];
#pragma unroll
                for (int r = 0; r < 4; r++) {
                    float xs = xp[r * 4 + kk];
                    acc[r][0] += xs * wv.x;
                    acc[r][1] += xs * wv.y;
                    acc[r][2] += xs * wv.z;
                    acc[r][3] += xs * wv.w;
                }
            }
        }
        float4 b1v = *(const float4*)&b1[col0 + cbase];
        float4 b2v = *(const float4*)&b2[col0 + cbase];
#pragma unroll
        for (int r = 0; r < 4; r++) {
            int row = row0 + rbase + r;
            if (row < N) {
                float rr = rvec[row];
                float4 o = make_float4(acc[r][0] + rr * b1v.x + b2v.x,
                                       acc[r][1] + rr * b1v.y + b2v.y,
                                       acc[r][2] + rr * b1v.z + b2v.z,
                                       acc[r][3] + rr * b1v.w + b2v.w);
                *(float4*)&out[(size_t)row * M + col0 + cbase] = o;
            }
        }
    }
}

// 128-col aggregation, quarter-wave uint4 gathers. Wave per dst; parity
// p = lane>>4 handles edges e+4j+p; lane c = lane&15 owns cols {8c..8c+7}
// via one uint4 (16 B) load -> one load instr = 4 rows (1 KB).
// WR: also emit r[d] = dinv[d]*sum(dinv[src]) (rank-1 bias, = A*ones).
template <bool PRE, bool WR>
__global__ __launch_bounds__(256) void agg_kernel(
    const unsigned short* __restrict__ Y, const int* __restrict__ offsets,
    const int* __restrict__ esrc, const float* __restrict__ dinv,
    unsigned short* __restrict__ out, float* __restrict__ rout, int N) {
    int wid = (blockIdx.x * blockDim.x + threadIdx.x) >> 6;
    int lane = threadIdx.x & 63;
    if (wid >= N) return;
    int beg = offsets[wid], end = offsets[wid + 1];
    int p = lane >> 4;
    int c = lane & 15;
    const uint4* Yu4 = (const uint4*)Y;   // row = 16 uint4 (256 B)
    float a0 = 0.f, a1 = 0.f, a2 = 0.f, a3 = 0.f;
    float a4 = 0.f, a5 = 0.f, a6 = 0.f, a7 = 0.f, ad = 0.f;
    int e = beg;
    for (; e + 16 <= end; e += 16) {
        int ss[4];
#pragma unroll
        for (int j = 0; j < 4; j++) ss[j] = esrc[e + 4 * j + p];
        uint4 vv[4];
#pragma unroll
        for (int j = 0; j < 4; j++) vv[j] = Yu4[(size_t)ss[j] * 16 + c];
        if (WR) {
#pragma unroll
            for (int j = 0; j < 4; j++) ad += dinv[ss[j]];
        }
#pragma unroll
        for (int j = 0; j < 4; j++) {
            a0 += bf2f_lo(vv[j].x); a1 += bf2f_hi(vv[j].x);
            a2 += bf2f_lo(vv[j].y); a3 += bf2f_hi(vv[j].y);
            a4 += bf2f_lo(vv[j].z); a5 += bf2f_hi(vv[j].z);
            a6 += bf2f_lo(vv[j].w); a7 += bf2f_hi(vv[j].w);
        }
    }
    for (; e + 4 <= end; e += 4) {
        int s = esrc[e + p];
        uint4 v = Yu4[(size_t)s * 16 + c];
        if (WR) ad += dinv[s];
        a0 += bf2f_lo(v.x); a1 += bf2f_hi(v.x);
        a2 += bf2f_lo(v.y); a3 += bf2f_hi(v.y);
        a4 += bf2f_lo(v.z); a5 += bf2f_hi(v.z);
        a6 += bf2f_lo(v.w); a7 += bf2f_hi(v.w);
    }
    int rem = end - e;
    if (p < rem) {
        int s = esrc[e + p];
        uint4 v = Yu4[(size_t)s * 16 + c];
        if (WR) ad += dinv[s];
        a0 += bf2f_lo(v.x); a1 += bf2f_hi(v.x);
        a2 += bf2f_lo(v.y); a3 += bf2f_hi(v.y);
        a4 += bf2f_lo(v.z); a5 += bf2f_hi(v.z);
        a6 += bf2f_lo(v.w); a7 += bf2f_hi(v.w);
    }
    a0 += __shfl_xor(a0, 16); a1 += __shfl_xor(a1, 16);
    a2 += __shfl_xor(a2, 16); a3 += __shfl_xor(a3, 16);
    a4 += __shfl_xor(a4, 16); a5 += __shfl_xor(a5, 16);
    a6 += __shfl_xor(a6, 16); a7 += __shfl_xor(a7, 16);
    a0 += __shfl_xor(a0, 32); a1 += __shfl_xor(a1, 32);
    a2 += __shfl_xor(a2, 32); a3 += __shfl_xor(a3, 32);
    a4 += __shfl_xor(a4, 32); a5 += __shfl_xor(a5, 32);
    a6 += __shfl_xor(a6, 32); a7 += __shfl_xor(a7, 32);
    if (WR) { ad += __shfl_xor(ad, 16); ad += __shfl_xor(ad, 32); }
    if (lane < 16) {
        float dd = dinv[wid];
        float r0 = a0 * dd, r1 = a1 * dd, r2 = a2 * dd, r3 = a3 * dd;
        float r4 = a4 * dd, r5 = a5 * dd, r6 = a6 * dd, r7 = a7 * dd;
        if (PRE) {
            r0 *= dd; r1 *= dd; r2 *= dd; r3 *= dd;
            r4 *= dd; r5 *= dd; r6 *= dd; r7 *= dd;
        }
        uint4 o;
        o.x = packbf(r0, r1); o.y = packbf(r2, r3);
        o.z = packbf(r4, r5); o.w = packbf(r6, r7);
        ((uint4*)out)[(size_t)wid * 16 + c] = o;
        if (WR && lane == 0) rout[wid] = ad * dd;
    }
}

// Second encoder agg + fused VAE head epilogue, quarter-wave uint4.
// Input V = dinv*(A X Wc), Wc cols interleaved (even=mean, odd=lv).
// After reduce, lane c<16 holds interleaved cols {8c..8c+7} = (mean,lv)
// pairs for output cols {4c..4c+3}. mean = T + r*bc + b2c;
// z = noise*exp(.5 lv)+mean; zb = dinv*z (bf16, prescaled for decoder).
__global__ __launch_bounds__(256) void aggmeanlv_kernel(
    const unsigned short* __restrict__ Y, const int* __restrict__ offsets,
    const int* __restrict__ esrc, const float* __restrict__ dinv,
    const float* __restrict__ rvec, const float* __restrict__ bc,
    const float* __restrict__ b2c, const float* __restrict__ noise,
    float* __restrict__ mean, float* __restrict__ lv, float* __restrict__ z,
    unsigned short* __restrict__ zb, int N) {
    int wid = (blockIdx.x * blockDim.x + threadIdx.x) >> 6;
    int lane = threadIdx.x & 63;
    if (wid >= N) return;
    int beg = offsets[wid], end = offsets[wid + 1];
    int p = lane >> 4;
    int c = lane & 15;
    const uint4* Yu4 = (const uint4*)Y;
    float a0 = 0.f, a1 = 0.f, a2 = 0.f, a3 = 0.f;
    float a4 = 0.f, a5 = 0.f, a6 = 0.f, a7 = 0.f;
    int e = beg;
    for (; e + 16 <= end; e += 16) {
        int ss[4];
#pragma unroll
        for (int j = 0; j < 4; j++) ss[j] = esrc[e + 4 * j + p];
        uint4 vv[4];
#pragma unroll
        for (int j = 0; j < 4; j++) vv[j] = Yu4[(size_t)ss[j] * 16 + c];
#pragma unroll
        for (int j = 0; j < 4; j++) {
            a0 += bf2f_lo(vv[j].x); a1 += bf2f_hi(vv[j].x);
            a2 += bf2f_lo(vv[j].y); a3 += bf2f_hi(vv[j].y);
            a4 += bf2f_lo(vv[j].z); a5 += bf2f_hi(vv[j].z);
            a6 += bf2f_lo(vv[j].w); a7 += bf2f_hi(vv[j].w);
        }
    }
    for (; e + 4 <= end; e += 4) {
        int s = esrc[e + p];
        uint4 v = Yu4[(size_t)s * 16 + c];
        a0 += bf2f_lo(v.x); a1 += bf2f_hi(v.x);
        a2 += bf2f_lo(v.y); a3 += bf2f_hi(v.y);
        a4 += bf2f_lo(v.z); a5 += bf2f_hi(v.z);
        a6 += bf2f_lo(v.w); a7 += bf2f_hi(v.w);
    }
    int rem = end - e;
    if (p < rem) {
        int s = esrc[e + p];
        uint4 v = Yu4[(size_t)s * 16 + c];
        a0 += bf2f_lo(v.x); a1 += bf2f_hi(v.x);
        a2 += bf2f_lo(v.y); a3 += bf2f_hi(v.y);
        a4 += bf2f_lo(v.z); a5 += bf2f_hi(v.z);
        a6 += bf2f_lo(v.w); a7 += bf2f_hi(v.w);
    }
    a0 += __shfl_xor(a0, 16); a1 += __shfl_xor(a1, 16);
    a2 += __shfl_xor(a2, 16); a3 += __shfl_xor(a3, 16);
    a4 += __shfl_xor(a4, 16); a5 += __shfl_xor(a5, 16);
    a6 += __shfl_xor(a6, 16); a7 += __shfl_xor(a7, 16);
    a0 += __shfl_xor(a0, 32); a1 += __shfl_xor(a1, 32);
    a2 += __shfl_xor(a2, 32); a3 += __shfl_xor(a3, 32);
    a4 += __shfl_xor(a4, 32); a5 += __shfl_xor(a5, 32);
    a6 += __shfl_xor(a6, 32); a7 += __shfl_xor(a7, 32);
    if (lane < 16) {
        float dd = dinv[wid];
        float rr = rvec[wid];
        float4 bca = ((const float4*)bc)[2 * c];
        float4 bcb = ((const float4*)bc)[2 * c + 1];
        float4 b2a = ((const float4*)b2c)[2 * c];
        float4 b2b = ((const float4*)b2c)[2 * c + 1];
        float m0 = a0 * dd + rr * bca.x + b2a.x;
        float l0 = a1 * dd + rr * bca.y + b2a.y;
        float m1 = a2 * dd + rr * bca.z + b2a.z;
        float l1 = a3 * dd + rr * bca.w + b2a.w;
        float m2 = a4 * dd + rr * bcb.x + b2b.x;
        float l2 = a5 * dd + rr * bcb.y + b2b.y;
        float m3 = a6 * dd + rr * bcb.z + b2b.z;
        float l3 = a7 * dd + rr * bcb.w + b2b.w;
        float4 nv = ((const float4*)noise)[(size_t)wid * 16 + c];
        float z0 = nv.x * expf(0.5f * l0) + m0;
        float z1 = nv.y * expf(0.5f * l1) + m1;
        float z2 = nv.z * expf(0.5f * l2) + m2;
        float z3 = nv.w * expf(0.5f * l3) + m3;
        size_t o = (size_t)wid * 16 + c;
        ((float4*)mean)[o] = make_float4(m0, m1, m2, m3);
        ((float4*)lv)[o] = make_float4(l0, l1, l2, l3);
        ((float4*)z)[o] = make_float4(z0, z1, z2, z3);
        uint2 zq;
        zq.x = packbf(z0 * dd, z1 * dd);
        zq.y = packbf(z2 * dd, z3 * dd);
        ((uint2*)zb)[o] = zq;
    }
}

// 64-col aggregation (decoder, z-space), quarter-wave row-split: parity
// p = lane>>4 (0..3) handles edges e+4j+p; lane c = lane&15 owns cols
// {4c..4c+3} via one uint2 load (one load instruction = 4 rows = 512 B).
template <bool PRE>
__global__ __launch_bounds__(256) void agg64_kernel(
    const unsigned short* __restrict__ Y, const int* __restrict__ offsets,
    const int* __restrict__ esrc, const float* __restrict__ dinv,
    unsigned short* __restrict__ out, int N) {
    int wid = (blockIdx.x * blockDim.x + threadIdx.x) >> 6;
    int lane = threadIdx.x & 63;
    if (wid >= N) return;
    int beg = offsets[wid], end = offsets[wid + 1];
    int p = lane >> 4;
    int c = lane & 15;
    const uint2* Yu2 = (const uint2*)Y;   // row = 16 uint2 (128 B)
    float a0 = 0.f, a1 = 0.f, a2 = 0.f, a3 = 0.f;
    int e = beg;
    for (; e + 16 <= end; e += 16) {
        int ss[4];
#pragma unroll
        for (int j = 0; j < 4; j++) ss[j] = esrc[e + 4 * j + p];
        uint2 vv[4];
#pragma unroll
        for (int j = 0; j < 4; j++) vv[j] = Yu2[(size_t)ss[j] * 16 + c];
#pragma unroll
        for (int j = 0; j < 4; j++) {
            a0 += bf2f_lo(vv[j].x); a1 += bf2f_hi(vv[j].x);
            a2 += bf2f_lo(vv[j].y); a3 += bf2f_hi(vv[j].y);
        }
    }
    for (; e + 4 <= end; e += 4) {
        int s = esrc[e + p];
        uint2 v = Yu2[(size_t)s * 16 + c];
        a0 += bf2f_lo(v.x); a1 += bf2f_hi(v.x);
        a2 += bf2f_lo(v.y); a3 += bf2f_hi(v.y);
    }
    int rem = end - e;
    if (p < rem) {
        int s = esrc[e + p];
        uint2 v = Yu2[(size_t)s * 16 + c];
        a0 += bf2f_lo(v.x); a1 += bf2f_hi(v.x);
        a2 += bf2f_lo(v.y); a3 += bf2f_hi(v.y);
    }
    a0 += __shfl_xor(a0, 16);
    a1 += __shfl_xor(a1, 16);
    a2 += __shfl_xor(a2, 16);
    a3 += __shfl_xor(a3, 16);
    a0 += __shfl_xor(a0, 32);
    a1 += __shfl_xor(a1, 32);
    a2 += __shfl_xor(a2, 32);
    a3 += __shfl_xor(a3, 32);
    if (lane < 16) {
        float dd = dinv[wid];
        float r0 = a0 * dd, r1 = a1 * dd, r2 = a2 * dd, r3 = a3 * dd;
        if (PRE) { r0 *= dd; r1 *= dd; r2 *= dd; r3 *= dd; }
        uint2 o;
        o.x = packbf(r0, r1);
        o.y = packbf(r2, r3);
        ((uint2*)out)[(size_t)wid * 16 + c] = o;
    }
}

extern "C" void kernel_launch(void* const* d_in, const int* in_sizes, int n_in,
                              void* d_out, int out_size, void* d_ws,
                              size_t ws_size, hipStream_t stream) {
    const float* feature = (const float*)d_in[0];
    const int*   ei      = (const int*)d_in[1];
    const float* noise   = (const float*)d_in[2];
    const float* W_enc   = (const float*)d_in[3];
    const float* b_enc   = (const float*)d_in[4];
    const float* W_mean  = (const float*)d_in[5];
    const float* b_mean  = (const float*)d_in[6];
    const float* W_lv    = (const float*)d_in[7];
    const float* b_lv    = (const float*)d_in[8];
    const float* W_d1    = (const float*)d_in[9];
    const float* b_d1    = (const float*)d_in[10];
    const float* W_d2    = (const float*)d_in[11];
    const float* b_d2    = (const float*)d_in[12];

    int N = in_sizes[0] / 128;
    int E = in_sizes[1] / 2;
    int nb = (N + 255) >> 8;

    float* z_out    = (float*)d_out;
    float* mean_out = z_out + (size_t)N * 64;
    float* lv_out   = z_out + (size_t)N * 128;
    float* gout     = z_out + (size_t)N * 192;

    char* ws = (char*)d_ws;
    unsigned short* Ybf = (unsigned short*)ws; ws += (size_t)N * 128 * 2;
    unsigned short* Hbf = (unsigned short*)ws; ws += (size_t)N * 128 * 2;
    unsigned short* Zbf = (unsigned short*)ws; ws += (size_t)N * 64 * 2;
    int*   esrc  = (int*)ws;   ws += (size_t)(E + N) * 4;
    int*   offs  = (int*)ws;   ws += (size_t)(N + 1) * 4;
    float* dinv  = (float*)ws; ws += (size_t)N * 4;
    int*   gcnt  = (int*)ws;   ws += 256 * 8 * 4;
    int*   bbase = (int*)ws;   ws += 256 * 4;   // unused (kept for layout)
    float* rvec  = (float*)ws; ws += (size_t)N * 4;
    float* Wc    = (float*)ws; ws += 128 * 128 * 4;
    float* Wd    = (float*)ws; ws += 64 * 128 * 4;
    float* bc    = (float*)ws; ws += 128 * 4;
    float* b2c   = (float*)ws; ws += 128 * 4;
    float* bd12  = (float*)ws; ws += 128 * 4;
    (void)bbase;

    // `pairs` ALIASES Ybf+Hbf (CSR build completes before matmuls touch Ybf).
    uint2* pairs = (uint2*)Ybf;
    size_t pairRegion = (size_t)N * 128 * 2 * 2;
    int capS = 1536;
    int capMax = (int)(pairRegion / (256 * 8 * sizeof(uint2)));
    if (capS > capMax) capS = capMax;

    const int* src = ei;
    const int* dst = ei + E;
    int total = E + N;

    // ---- CSR build (coalesced counting sort; scan merged into build) ----
    zero_kernel<<<(256 * 8 + 255) / 256, 256, 0, stream>>>(gcnt, 256 * 8);
    bucketize_kernel<<<(total + 4095) / 4096, 256, 0, stream>>>(
        src, dst, E, N, capS, pairs, gcnt);
    build_kernel<<<nb, 256, 0, stream>>>(pairs, gcnt, capS, N, offs,
                                         dinv, esrc);

    // ---- collapsed weights (tiny) ----
    wcomb_kernel<<<(16384 + 8192 + 384 + 255) / 256, 256, 0, stream>>>(
        W_enc, b_enc, W_mean, b_mean, W_lv, b_lv, W_d1, b_d1, W_d2,
        Wc, bc, b2c, Wd, bd12);

    int gx = (N + 63) / 64;
    int aggBlocks = (int)(((size_t)N * 64 + 255) / 256);

    // ---- encoder: meanlv = A^2 X Wc + r*bc + b2c ----
    matmul_kernel<128, false, true><<<gx, 256, 0, stream>>>(
        feature, Wc, dinv, Ybf, N);                      // U = dinv*(X@Wc)
    agg_kernel<true, true><<<aggBlocks, 256, 0, stream>>>(
        Ybf, offs, esrc, dinv, Hbf, rvec, N);            // V = dinv*(A U), r
    aggmeanlv_kernel<<<aggBlocks, 256, 0, stream>>>(
        Hbf, offs, esrc, dinv, rvec, bc, b2c, noise,
        mean_out, lv_out, z_out, Zbf, N);                // mean/lv/z + zb

    // ---- decoder: out = A^2 z Wd + r*bd12 + bd2 ----
    agg64_kernel<true><<<aggBlocks, 256, 0, stream>>>(
        Zbf, offs, esrc, dinv, Ybf, N);                  // P = dinv*(A z)
    fused_out_kernel<<<gx, 256, 0, stream>>>(
        Ybf, offs, esrc, dinv, Wd, rvec, bd12, b_d2, gout, N);  // Q + matmul
}

// Round 10
// 388.553 us; speedup vs baseline: 1.0439x; 1.0439x over previous
//
#include <hip/hip_runtime.h>
#include <math.h>

// ---------------------------------------------------------------------------
// GCN-VAE fused pipeline for MI355X.
// R16: revert R15's gather-into-matmul fusion (it tied the latency-bound
// Q-gather to the matmul's 782-block grid: 3072 waves vs agg64's 50000 ->
// occupancy 28%, 74us vs the ~50us it replaced). Restore verified R14
// decoder tail (agg64 at full grid + standalone matmul_out). KEEP R15's
// scan-merged build_kernel (neutral-positive, one fewer launch).
// Everything else = verified R14 (393.8us).
// Aggs are at their measured structural floor (MSHR x latency ~3 TB/s fill,
// FETCH pinned at 165 MB across the R9->R14 MLP ladder 65->60us).
// ---------------------------------------------------------------------------

__device__ inline float bf2f_lo(unsigned int v) {
    return __uint_as_float(v << 16);
}
__device__ inline float bf2f_hi(unsigned int v) {
    return __uint_as_float(v & 0xFFFF0000u);
}
__device__ inline unsigned short f2bf(float f) {
    unsigned int u = __float_as_uint(f);
    return (unsigned short)((u + 0x7FFFu + ((u >> 16) & 1u)) >> 16);
}
__device__ inline unsigned int packbf(float a, float b) {
    return (unsigned int)f2bf(a) | ((unsigned int)f2bf(b) << 16);
}
__device__ inline unsigned int get_xcd() {
    unsigned int x;
    asm volatile("s_getreg_b32 %0, hwreg(HW_REG_XCC_ID)" : "=s"(x));
    return x & 7u;
}

__global__ void zero_kernel(int* __restrict__ p, int n) {
    int i = blockIdx.x * blockDim.x + threadIdx.x;
    if (i < n) p[i] = 0;
}

// Pass 1: bucket edges (+self-loops) by dst>>8 into per-(bucket,XCD) slices.
__global__ __launch_bounds__(256) void bucketize_kernel(
    const int* __restrict__ src, const int* __restrict__ dst, int E, int N,
    int capS, uint2* __restrict__ pairs, int* __restrict__ gcnt) {
    __shared__ int lcnt[256];
    __shared__ int lbase[256];
    int tid = threadIdx.x;
    int total = E + N;
    int base = blockIdx.x * 4096;
    unsigned int x = get_xcd();
    lcnt[tid] = 0;
    __syncthreads();
    int d[16], s[16], rk[16];
#pragma unroll
    for (int j = 0; j < 16; j++) {
        int idx = base + j * 256 + tid;
        d[j] = -1;
        if (idx < total) {
            if (idx < E) { d[j] = dst[idx]; s[j] = src[idx]; }
            else         { d[j] = idx - E; s[j] = d[j]; }
            rk[j] = atomicAdd(&lcnt[d[j] >> 8], 1);
        }
    }
    __syncthreads();
    if (lcnt[tid] > 0) lbase[tid] = atomicAdd(&gcnt[tid * 8 + (int)x],
                                              lcnt[tid]);
    __syncthreads();
#pragma unroll
    for (int j = 0; j < 16; j++) {
        if (d[j] >= 0) {
            int b = d[j] >> 8;
            int pos = lbase[b] + rk[j];
            if (pos < capS)
                pairs[(size_t)(b * 8 + (int)x) * capS + pos] =
                    make_uint2((unsigned)d[j], (unsigned)s[j]);
        }
    }
}

// Pass 2 (merged scan + sort): one block per bucket. Each block redundantly
// computes the global bucket-total scan from gcnt in LDS, then LDS counting
// sort by dst&255 and fully coalesced writes of offs/dinv/esrc.
// Block 0 writes offs[N].
__global__ __launch_bounds__(256) void build_kernel(
    const uint2* __restrict__ pairs, const int* __restrict__ gcnt, int capS,
    int N, int* __restrict__ offs, float* __restrict__ dinv,
    int* __restrict__ esrc) {
    __shared__ int gtot[256];
    __shared__ int cnt[256];
    __shared__ int loff[256];
    __shared__ int cur[256];
    __shared__ int S[10240];
    int b = blockIdx.x;
    int tid = threadIdx.x;

    // global bucket scan (replicated per block)
    int tb = 0;
#pragma unroll
    for (int x = 0; x < 8; x++) {
        int v = gcnt[tid * 8 + x];
        if (v > capS) v = capS;
        tb += v;
    }
    gtot[tid] = tb;
    cnt[tid] = 0;
    __syncthreads();
    for (int off = 1; off < 256; off <<= 1) {
        int u = (tid >= off) ? gtot[tid - off] : 0;
        __syncthreads();
        gtot[tid] += u;
        __syncthreads();
    }
    if (b == 0 && tid == 255) offs[N] = gtot[255];
    int base = (b == 0) ? 0 : gtot[b - 1];

    int szx[8];
#pragma unroll
    for (int x = 0; x < 8; x++) {
        int v = gcnt[b * 8 + x];
        if (v > capS) v = capS;
        szx[x] = v;
    }
#pragma unroll
    for (int x = 0; x < 8; x++) {
        const uint2* bp = pairs + (size_t)(b * 8 + x) * capS;
        for (int i = tid; i < szx[x]; i += 256)
            atomicAdd(&cnt[bp[i].x & 255u], 1);
    }
    __syncthreads();
    int c = cnt[tid];
    loff[tid] = c;
    __syncthreads();
    for (int off = 1; off < 256; off <<= 1) {
        int u = (tid >= off) ? loff[tid - off] : 0;
        __syncthreads();
        loff[tid] += u;
        __syncthreads();
    }
    int excl = loff[tid] - c;
    cur[tid] = excl;
    int total = loff[255];
    int d0 = b << 8;
    if (d0 + tid < N) {
        offs[d0 + tid] = base + excl;
        dinv[d0 + tid] = rsqrtf((float)c);   // c >= 1 (self-loop)
    }
    __syncthreads();
#pragma unroll
    for (int x = 0; x < 8; x++) {
        const uint2* bp = pairs + (size_t)(b * 8 + x) * capS;
        for (int i = tid; i < szx[x]; i += 256) {
            uint2 p = bp[i];
            int pos = atomicAdd(&cur[p.x & 255u], 1);
            if (pos < 10240) S[pos] = (int)p.y;
        }
    }
    __syncthreads();
    if (total > 10240) total = 10240;
    for (int j = tid; j < total; j += 256) esrc[base + j] = S[j];
}

// Collapse weights on-device (tiny):
//  Wc[k][2j]=sum_m We[k][m]*Wm[m][j], Wc[k][2j+1]=sum_m We[k][m]*Wl[m][j]
//  Wd[k][c]=sum_m Wd1[k][m]*Wd2[m][c]
//  bc[2j]=be@Wm, bc[2j+1]=be@Wl; b2c = interleave(bm,bl); bd12 = bd1@Wd2
__global__ __launch_bounds__(256) void wcomb_kernel(
    const float* __restrict__ We, const float* __restrict__ be,
    const float* __restrict__ Wm, const float* __restrict__ bm,
    const float* __restrict__ Wl, const float* __restrict__ bl,
    const float* __restrict__ Wd1, const float* __restrict__ bd1,
    const float* __restrict__ Wd2, float* __restrict__ Wc,
    float* __restrict__ bc, float* __restrict__ b2c, float* __restrict__ Wd,
    float* __restrict__ bd12) {
    int i = blockIdx.x * 256 + threadIdx.x;
    if (i < 16384) {                          // Wc (128x128 interleaved)
        int k = i >> 7, c = i & 127, j = c >> 1;
        const float* Wx = (c & 1) ? Wl : Wm;
        float s = 0.f;
        for (int m = 0; m < 128; m++) s += We[k * 128 + m] * Wx[m * 64 + j];
        Wc[k * 128 + c] = s;
    } else if (i < 16384 + 8192) {            // Wd (64x128)
        int t = i - 16384;
        int k = t >> 7, c = t & 127;
        float s = 0.f;
        for (int m = 0; m < 128; m++) s += Wd1[k * 128 + m] * Wd2[m * 128 + c];
        Wd[k * 128 + c] = s;
    } else if (i < 16384 + 8192 + 128) {      // bc
        int c = i - (16384 + 8192), j = c >> 1;
        const float* Wx = (c & 1) ? Wl : Wm;
        float s = 0.f;
        for (int m = 0; m < 128; m++) s += be[m] * Wx[m * 64 + j];
        bc[c] = s;
    } else if (i < 16384 + 8192 + 256) {      // b2c
        int c = i - (16384 + 8192 + 128);
        b2c[c] = (c & 1) ? bl[c >> 1] : bm[c >> 1];
    } else if (i < 16384 + 8192 + 384) {      // bd12
        int c = i - (16384 + 8192 + 256);
        float s = 0.f;
        for (int m = 0; m < 128; m++) s += bd1[m] * Wd2[m * 128 + c];
        bd12[c] = s;
    }
}

// Tiled matmul: out[N,128] = X[N,K] @ W[K,128], bf16 out, dinv row prescale.
// Both column halves computed by one block (X staged to LDS once).
template <int K, bool XBF, bool SCALE>
__global__ __launch_bounds__(256, 4) void matmul_kernel(
    const void* __restrict__ Xv, const float* __restrict__ W,
    const float* __restrict__ dinv, unsigned short* __restrict__ out, int N) {
    const int M = 128;
    const int KP = K + 4;
    __shared__ float ldsW[K][64];
    __shared__ float ldsX[64][KP];
    int tid = threadIdx.x;
    int row0 = blockIdx.x * 64;

    int maxr = N - row0; if (maxr > 64) maxr = 64;
    if (XBF) {
        const unsigned short* X = (const unsigned short*)Xv;
        for (int i = tid; i < maxr * (K / 8); i += 256) {
            int r = i / (K / 8), c8 = i % (K / 8);
            uint4 u = *(const uint4*)&X[(size_t)(row0 + r) * K + c8 * 8];
            float* dp = &ldsX[r][c8 * 8];
            dp[0] = bf2f_lo(u.x); dp[1] = bf2f_hi(u.x);
            dp[2] = bf2f_lo(u.y); dp[3] = bf2f_hi(u.y);
            dp[4] = bf2f_lo(u.z); dp[5] = bf2f_hi(u.z);
            dp[6] = bf2f_lo(u.w); dp[7] = bf2f_hi(u.w);
        }
    } else {
        const float* X = (const float*)Xv;
        for (int i = tid; i < maxr * (K / 4); i += 256) {
            int r = i / (K / 4), k4 = i % (K / 4);
            *(float4*)&ldsX[r][k4 * 4] =
                *(const float4*)&X[(size_t)(row0 + r) * K + k4 * 4];
        }
    }

    int cg = tid & 15, rg = tid >> 4;
    int rbase = rg * 4, cbase = cg * 4;

    for (int half = 0; half < 2; half++) {
        int col0 = half * 64;
        if (half) __syncthreads();   // protect ldsW reuse vs prior reads
        for (int i = tid; i < K * 16; i += 256) {
            int k = i >> 4, j4 = i & 15;
            ((float4*)&ldsW[k][0])[j4] =
                *(const float4*)&W[(size_t)k * M + col0 + j4 * 4];
        }
        __syncthreads();

        float acc[4][4] = {};
#pragma unroll 2
        for (int k = 0; k < K; k += 4) {
            float4 xv[4];
#pragma unroll
            for (int r = 0; r < 4; r++)
                xv[r] = *(const float4*)&ldsX[rbase + r][k];
            const float* xp = (const float*)xv;
#pragma unroll
            for (int kk = 0; kk < 4; kk++) {
                float4 wv = *(const float4*)&ldsW[k + kk][cbase];
#pragma unroll
                for (int r = 0; r < 4; r++) {
                    float xs = xp[r * 4 + kk];
                    acc[r][0] += xs * wv.x;
                    acc[r][1] += xs * wv.y;
                    acc[r][2] += xs * wv.z;
                    acc[r][3] += xs * wv.w;
                }
            }
        }
#pragma unroll
        for (int r = 0; r < 4; r++) {
            int row = row0 + rbase + r;
            if (row < N) {
                float sc = SCALE ? dinv[row] : 1.0f;
                ushort4 o;
                o.x = f2bf(acc[r][0] * sc); o.y = f2bf(acc[r][1] * sc);
                o.z = f2bf(acc[r][2] * sc); o.w = f2bf(acc[r][3] * sc);
                *(ushort4*)&out[(size_t)row * M + col0 + cbase] = o;
            }
        }
    }
}

// Final matmul: out[N,128] = Q[N,64]@Wd + r[row]*b1[col] + b2[col], fp32 out.
// Both column halves per block (Q staged once).
__global__ __launch_bounds__(256, 4) void matmul_out_kernel(
    const unsigned short* __restrict__ X, const float* __restrict__ W,
    const float* __restrict__ rvec, const float* __restrict__ b1,
    const float* __restrict__ b2, float* __restrict__ out, int N) {
    const int K = 64, M = 128;
    const int KP = K + 4;
    __shared__ float ldsW[K][64];
    __shared__ float ldsX[64][KP];
    int tid = threadIdx.x;
    int row0 = blockIdx.x * 64;

    int maxr = N - row0; if (maxr > 64) maxr = 64;
    for (int i = tid; i < maxr * (K / 8); i += 256) {
        int r = i / (K / 8), c8 = i % (K / 8);
        uint4 u = *(const uint4*)&X[(size_t)(row0 + r) * K + c8 * 8];
        float* dp = &ldsX[r][c8 * 8];
        dp[0] = bf2f_lo(u.x); dp[1] = bf2f_hi(u.x);
        dp[2] = bf2f_lo(u.y); dp[3] = bf2f_hi(u.y);
        dp[4] = bf2f_lo(u.z); dp[5] = bf2f_hi(u.z);
        dp[6] = bf2f_lo(u.w); dp[7] = bf2f_hi(u.w);
    }

    int cg = tid & 15, rg = tid >> 4;
    int rbase = rg * 4, cbase = cg * 4;

    for (int half = 0; half < 2; half++) {
        int col0 = half * 64;
        if (half) __syncthreads();
        for (int i = tid; i < K * 16; i += 256) {
            int k = i >> 4, j4 = i & 15;
            ((float4*)&ldsW[k][0])[j4] =
                *(const float4*)&W[(size_t)k * M + col0 + j4 * 4];
        }
        __syncthreads();

        float acc[4][4] = {};
#pragma unroll 2
        for (int k = 0; k < K; k += 4) {
            float4 xv[4];
#pragma unroll
            for (int r = 0; r < 4; r++)
                xv[r] = *(const float4*)&ldsX[rbase + r][k];
            const float* xp = (const float*)xv;
#pragma unroll
            for (int kk = 0; kk < 4; kk++) {
                float4 wv = *(const float4*)&ldsW[k + kk][cbase];
#pragma unroll
                for (int r = 0; r < 4; r++) {
                    float xs = xp[r * 4 + kk];
                    acc[r][0] += xs * wv.x;
                    acc[r][1] += xs * wv.y;
                    acc[r][2] += xs * wv.z;
                    acc[r][3] += xs * wv.w;
                }
            }
        }
        float4 b1v = *(const float4*)&b1[col0 + cbase];
        float4 b2v = *(const float4*)&b2[col0 + cbase];
#pragma unroll
        for (int r = 0; r < 4; r++) {
            int row = row0 + rbase + r;
            if (row < N) {
                float rr = rvec[row];
                float4 o = make_float4(acc[r][0] + rr * b1v.x + b2v.x,
                                       acc[r][1] + rr * b1v.y + b2v.y,
                                       acc[r][2] + rr * b1v.z + b2v.z,
                                       acc[r][3] + rr * b1v.w + b2v.w);
                *(float4*)&out[(size_t)row * M + col0 + cbase] = o;
            }
        }
    }
}

// 128-col aggregation, quarter-wave uint4 gathers. Wave per dst; parity
// p = lane>>4 handles edges e+4j+p; lane c = lane&15 owns cols {8c..8c+7}
// via one uint4 (16 B) load -> one load instr = 4 rows (1 KB).
// WR: also emit r[d] = dinv[d]*sum(dinv[src]) (rank-1 bias, = A*ones).
template <bool PRE, bool WR>
__global__ __launch_bounds__(256) void agg_kernel(
    const unsigned short* __restrict__ Y, const int* __restrict__ offsets,
    const int* __restrict__ esrc, const float* __restrict__ dinv,
    unsigned short* __restrict__ out, float* __restrict__ rout, int N) {
    int wid = (blockIdx.x * blockDim.x + threadIdx.x) >> 6;
    int lane = threadIdx.x & 63;
    if (wid >= N) return;
    int beg = offsets[wid], end = offsets[wid + 1];
    int p = lane >> 4;
    int c = lane & 15;
    const uint4* Yu4 = (const uint4*)Y;   // row = 16 uint4 (256 B)
    float a0 = 0.f, a1 = 0.f, a2 = 0.f, a3 = 0.f;
    float a4 = 0.f, a5 = 0.f, a6 = 0.f, a7 = 0.f, ad = 0.f;
    int e = beg;
    for (; e + 16 <= end; e += 16) {
        int ss[4];
#pragma unroll
        for (int j = 0; j < 4; j++) ss[j] = esrc[e + 4 * j + p];
        uint4 vv[4];
#pragma unroll
        for (int j = 0; j < 4; j++) vv[j] = Yu4[(size_t)ss[j] * 16 + c];
        if (WR) {
#pragma unroll
            for (int j = 0; j < 4; j++) ad += dinv[ss[j]];
        }
#pragma unroll
        for (int j = 0; j < 4; j++) {
            a0 += bf2f_lo(vv[j].x); a1 += bf2f_hi(vv[j].x);
            a2 += bf2f_lo(vv[j].y); a3 += bf2f_hi(vv[j].y);
            a4 += bf2f_lo(vv[j].z); a5 += bf2f_hi(vv[j].z);
            a6 += bf2f_lo(vv[j].w); a7 += bf2f_hi(vv[j].w);
        }
    }
    for (; e + 4 <= end; e += 4) {
        int s = esrc[e + p];
        uint4 v = Yu4[(size_t)s * 16 + c];
        if (WR) ad += dinv[s];
        a0 += bf2f_lo(v.x); a1 += bf2f_hi(v.x);
        a2 += bf2f_lo(v.y); a3 += bf2f_hi(v.y);
        a4 += bf2f_lo(v.z); a5 += bf2f_hi(v.z);
        a6 += bf2f_lo(v.w); a7 += bf2f_hi(v.w);
    }
    int rem = end - e;
    if (p < rem) {
        int s = esrc[e + p];
        uint4 v = Yu4[(size_t)s * 16 + c];
        if (WR) ad += dinv[s];
        a0 += bf2f_lo(v.x); a1 += bf2f_hi(v.x);
        a2 += bf2f_lo(v.y); a3 += bf2f_hi(v.y);
        a4 += bf2f_lo(v.z); a5 += bf2f_hi(v.z);
        a6 += bf2f_lo(v.w); a7 += bf2f_hi(v.w);
    }
    a0 += __shfl_xor(a0, 16); a1 += __shfl_xor(a1, 16);
    a2 += __shfl_xor(a2, 16); a3 += __shfl_xor(a3, 16);
    a4 += __shfl_xor(a4, 16); a5 += __shfl_xor(a5, 16);
    a6 += __shfl_xor(a6, 16); a7 += __shfl_xor(a7, 16);
    a0 += __shfl_xor(a0, 32); a1 += __shfl_xor(a1, 32);
    a2 += __shfl_xor(a2, 32); a3 += __shfl_xor(a3, 32);
    a4 += __shfl_xor(a4, 32); a5 += __shfl_xor(a5, 32);
    a6 += __shfl_xor(a6, 32); a7 += __shfl_xor(a7, 32);
    if (WR) { ad += __shfl_xor(ad, 16); ad += __shfl_xor(ad, 32); }
    if (lane < 16) {
        float dd = dinv[wid];
        float r0 = a0 * dd, r1 = a1 * dd, r2 = a2 * dd, r3 = a3 * dd;
        float r4 = a4 * dd, r5 = a5 * dd, r6 = a6 * dd, r7 = a7 * dd;
        if (PRE) {
            r0 *= dd; r1 *= dd; r2 *= dd; r3 *= dd;
            r4 *= dd; r5 *= dd; r6 *= dd; r7 *= dd;
        }
        uint4 o;
        o.x = packbf(r0, r1); o.y = packbf(r2, r3);
        o.z = packbf(r4, r5); o.w = packbf(r6, r7);
        ((uint4*)out)[(size_t)wid * 16 + c] = o;
        if (WR && lane == 0) rout[wid] = ad * dd;
    }
}

// Second encoder agg + fused VAE head epilogue, quarter-wave uint4.
// Input V = dinv*(A X Wc), Wc cols interleaved (even=mean, odd=lv).
// After reduce, lane c<16 holds interleaved cols {8c..8c+7} = (mean,lv)
// pairs for output cols {4c..4c+3}. mean = T + r*bc + b2c;
// z = noise*exp(.5 lv)+mean; zb = dinv*z (bf16, prescaled for decoder).
__global__ __launch_bounds__(256) void aggmeanlv_kernel(
    const unsigned short* __restrict__ Y, const int* __restrict__ offsets,
    const int* __restrict__ esrc, const float* __restrict__ dinv,
    const float* __restrict__ rvec, const float* __restrict__ bc,
    const float* __restrict__ b2c, const float* __restrict__ noise,
    float* __restrict__ mean, float* __restrict__ lv, float* __restrict__ z,
    unsigned short* __restrict__ zb, int N) {
    int wid = (blockIdx.x * blockDim.x + threadIdx.x) >> 6;
    int lane = threadIdx.x & 63;
    if (wid >= N) return;
    int beg = offsets[wid], end = offsets[wid + 1];
    int p = lane >> 4;
    int c = lane & 15;
    const uint4* Yu4 = (const uint4*)Y;
    float a0 = 0.f, a1 = 0.f, a2 = 0.f, a3 = 0.f;
    float a4 = 0.f, a5 = 0.f, a6 = 0.f, a7 = 0.f;
    int e = beg;
    for (; e + 16 <= end; e += 16) {
        int ss[4];
#pragma unroll
        for (int j = 0; j < 4; j++) ss[j] = esrc[e + 4 * j + p];
        uint4 vv[4];
#pragma unroll
        for (int j = 0; j < 4; j++) vv[j] = Yu4[(size_t)ss[j] * 16 + c];
#pragma unroll
        for (int j = 0; j < 4; j++) {
            a0 += bf2f_lo(vv[j].x); a1 += bf2f_hi(vv[j].x);
            a2 += bf2f_lo(vv[j].y); a3 += bf2f_hi(vv[j].y);
            a4 += bf2f_lo(vv[j].z); a5 += bf2f_hi(vv[j].z);
            a6 += bf2f_lo(vv[j].w); a7 += bf2f_hi(vv[j].w);
        }
    }
    for (; e + 4 <= end; e += 4) {
        int s = esrc[e + p];
        uint4 v = Yu4[(size_t)s * 16 + c];
        a0 += bf2f_lo(v.x); a1 += bf2f_hi(v.x);
        a2 += bf2f_lo(v.y); a3 += bf2f_hi(v.y);
        a4 += bf2f_lo(v.z); a5 += bf2f_hi(v.z);
        a6 += bf2f_lo(v.w); a7 += bf2f_hi(v.w);
    }
    int rem = end - e;
    if (p < rem) {
        int s = esrc[e + p];
        uint4 v = Yu4[(size_t)s * 16 + c];
        a0 += bf2f_lo(v.x); a1 += bf2f_hi(v.x);
        a2 += bf2f_lo(v.y); a3 += bf2f_hi(v.y);
        a4 += bf2f_lo(v.z); a5 += bf2f_hi(v.z);
        a6 += bf2f_lo(v.w); a7 += bf2f_hi(v.w);
    }
    a0 += __shfl_xor(a0, 16); a1 += __shfl_xor(a1, 16);
    a2 += __shfl_xor(a2, 16); a3 += __shfl_xor(a3, 16);
    a4 += __shfl_xor(a4, 16); a5 += __shfl_xor(a5, 16);
    a6 += __shfl_xor(a6, 16); a7 += __shfl_xor(a7, 16);
    a0 += __shfl_xor(a0, 32); a1 += __shfl_xor(a1, 32);
    a2 += __shfl_xor(a2, 32); a3 += __shfl_xor(a3, 32);
    a4 += __shfl_xor(a4, 32); a5 += __shfl_xor(a5, 32);
    a6 += __shfl_xor(a6, 32); a7 += __shfl_xor(a7, 32);
    if (lane < 16) {
        float dd = dinv[wid];
        float rr = rvec[wid];
        float4 bca = ((const float4*)bc)[2 * c];
        float4 bcb = ((const float4*)bc)[2 * c + 1];
        float4 b2a = ((const float4*)b2c)[2 * c];
        float4 b2b = ((const float4*)b2c)[2 * c + 1];
        float m0 = a0 * dd + rr * bca.x + b2a.x;
        float l0 = a1 * dd + rr * bca.y + b2a.y;
        float m1 = a2 * dd + rr * bca.z + b2a.z;
        float l1 = a3 * dd + rr * bca.w + b2a.w;
        float m2 = a4 * dd + rr * bcb.x + b2b.x;
        float l2 = a5 * dd + rr * bcb.y + b2b.y;
        float m3 = a6 * dd + rr * bcb.z + b2b.z;
        float l3 = a7 * dd + rr * bcb.w + b2b.w;
        float4 nv = ((const float4*)noise)[(size_t)wid * 16 + c];
        float z0 = nv.x * expf(0.5f * l0) + m0;
        float z1 = nv.y * expf(0.5f * l1) + m1;
        float z2 = nv.z * expf(0.5f * l2) + m2;
        float z3 = nv.w * expf(0.5f * l3) + m3;
        size_t o = (size_t)wid * 16 + c;
        ((float4*)mean)[o] = make_float4(m0, m1, m2, m3);
        ((float4*)lv)[o] = make_float4(l0, l1, l2, l3);
        ((float4*)z)[o] = make_float4(z0, z1, z2, z3);
        uint2 zq;
        zq.x = packbf(z0 * dd, z1 * dd);
        zq.y = packbf(z2 * dd, z3 * dd);
        ((uint2*)zb)[o] = zq;
    }
}

// 64-col aggregation (decoder, z-space), quarter-wave row-split: parity
// p = lane>>4 (0..3) handles edges e+4j+p; lane c = lane&15 owns cols
// {4c..4c+3} via one uint2 load (one load instruction = 4 rows = 512 B).
template <bool PRE>
__global__ __launch_bounds__(256) void agg64_kernel(
    const unsigned short* __restrict__ Y, const int* __restrict__ offsets,
    const int* __restrict__ esrc, const float* __restrict__ dinv,
    unsigned short* __restrict__ out, int N) {
    int wid = (blockIdx.x * blockDim.x + threadIdx.x) >> 6;
    int lane = threadIdx.x & 63;
    if (wid >= N) return;
    int beg = offsets[wid], end = offsets[wid + 1];
    int p = lane >> 4;
    int c = lane & 15;
    const uint2* Yu2 = (const uint2*)Y;   // row = 16 uint2 (128 B)
    float a0 = 0.f, a1 = 0.f, a2 = 0.f, a3 = 0.f;
    int e = beg;
    for (; e + 16 <= end; e += 16) {
        int ss[4];
#pragma unroll
        for (int j = 0; j < 4; j++) ss[j] = esrc[e + 4 * j + p];
        uint2 vv[4];
#pragma unroll
        for (int j = 0; j < 4; j++) vv[j] = Yu2[(size_t)ss[j] * 16 + c];
#pragma unroll
        for (int j = 0; j < 4; j++) {
            a0 += bf2f_lo(vv[j].x); a1 += bf2f_hi(vv[j].x);
            a2 += bf2f_lo(vv[j].y); a3 += bf2f_hi(vv[j].y);
        }
    }
    for (; e + 4 <= end; e += 4) {
        int s = esrc[e + p];
        uint2 v = Yu2[(size_t)s * 16 + c];
        a0 += bf2f_lo(v.x); a1 += bf2f_hi(v.x);
        a2 += bf2f_lo(v.y); a3 += bf2f_hi(v.y);
    }
    int rem = end - e;
    if (p < rem) {
        int s = esrc[e + p];
        uint2 v = Yu2[(size_t)s * 16 + c];
        a0 += bf2f_lo(v.x); a1 += bf2f_hi(v.x);
        a2 += bf2f_lo(v.y); a3 += bf2f_hi(v.y);
    }
    a0 += __shfl_xor(a0, 16);
    a1 += __shfl_xor(a1, 16);
    a2 += __shfl_xor(a2, 16);
    a3 += __shfl_xor(a3, 16);
    a0 += __shfl_xor(a0, 32);
    a1 += __shfl_xor(a1, 32);
    a2 += __shfl_xor(a2, 32);
    a3 += __shfl_xor(a3, 32);
    if (lane < 16) {
        float dd = dinv[wid];
        float r0 = a0 * dd, r1 = a1 * dd, r2 = a2 * dd, r3 = a3 * dd;
        if (PRE) { r0 *= dd; r1 *= dd; r2 *= dd; r3 *= dd; }
        uint2 o;
        o.x = packbf(r0, r1);
        o.y = packbf(r2, r3);
        ((uint2*)out)[(size_t)wid * 16 + c] = o;
    }
}

extern "C" void kernel_launch(void* const* d_in, const int* in_sizes, int n_in,
                              void* d_out, int out_size, void* d_ws,
                              size_t ws_size, hipStream_t stream) {
    const float* feature = (const float*)d_in[0];
    const int*   ei      = (const int*)d_in[1];
    const float* noise   = (const float*)d_in[2];
    const float* W_enc   = (const float*)d_in[3];
    const float* b_enc   = (const float*)d_in[4];
    const float* W_mean  = (const float*)d_in[5];
    const float* b_mean  = (const float*)d_in[6];
    const float* W_lv    = (const float*)d_in[7];
    const float* b_lv    = (const float*)d_in[8];
    const float* W_d1    = (const float*)d_in[9];
    const float* b_d1    = (const float*)d_in[10];
    const float* W_d2    = (const float*)d_in[11];
    const float* b_d2    = (const float*)d_in[12];

    int N = in_sizes[0] / 128;
    int E = in_sizes[1] / 2;
    int nb = (N + 255) >> 8;

    float* z_out    = (float*)d_out;
    float* mean_out = z_out + (size_t)N * 64;
    float* lv_out   = z_out + (size_t)N * 128;
    float* gout     = z_out + (size_t)N * 192;

    char* ws = (char*)d_ws;
    unsigned short* Ybf = (unsigned short*)ws; ws += (size_t)N * 128 * 2;
    unsigned short* Hbf = (unsigned short*)ws; ws += (size_t)N * 128 * 2;
    unsigned short* Zbf = (unsigned short*)ws; ws += (size_t)N * 64 * 2;
    int*   esrc  = (int*)ws;   ws += (size_t)(E + N) * 4;
    int*   offs  = (int*)ws;   ws += (size_t)(N + 1) * 4;
    float* dinv  = (float*)ws; ws += (size_t)N * 4;
    int*   gcnt  = (int*)ws;   ws += 256 * 8 * 4;
    int*   bbase = (int*)ws;   ws += 256 * 4;   // unused (kept for layout)
    float* rvec  = (float*)ws; ws += (size_t)N * 4;
    float* Wc    = (float*)ws; ws += 128 * 128 * 4;
    float* Wd    = (float*)ws; ws += 64 * 128 * 4;
    float* bc    = (float*)ws; ws += 128 * 4;
    float* b2c   = (float*)ws; ws += 128 * 4;
    float* bd12  = (float*)ws; ws += 128 * 4;
    (void)bbase;

    // `pairs` ALIASES Ybf+Hbf (CSR build completes before matmuls touch Ybf).
    uint2* pairs = (uint2*)Ybf;
    size_t pairRegion = (size_t)N * 128 * 2 * 2;
    int capS = 1536;
    int capMax = (int)(pairRegion / (256 * 8 * sizeof(uint2)));
    if (capS > capMax) capS = capMax;

    const int* src = ei;
    const int* dst = ei + E;
    int total = E + N;

    // ---- CSR build (coalesced counting sort; scan merged into build) ----
    zero_kernel<<<(256 * 8 + 255) / 256, 256, 0, stream>>>(gcnt, 256 * 8);
    bucketize_kernel<<<(total + 4095) / 4096, 256, 0, stream>>>(
        src, dst, E, N, capS, pairs, gcnt);
    build_kernel<<<nb, 256, 0, stream>>>(pairs, gcnt, capS, N, offs,
                                         dinv, esrc);

    // ---- collapsed weights (tiny) ----
    wcomb_kernel<<<(16384 + 8192 + 384 + 255) / 256, 256, 0, stream>>>(
        W_enc, b_enc, W_mean, b_mean, W_lv, b_lv, W_d1, b_d1, W_d2,
        Wc, bc, b2c, Wd, bd12);

    int gx = (N + 63) / 64;
    int aggBlocks = (int)(((size_t)N * 64 + 255) / 256);

    // ---- encoder: meanlv = A^2 X Wc + r*bc + b2c ----
    matmul_kernel<128, false, true><<<gx, 256, 0, stream>>>(
        feature, Wc, dinv, Ybf, N);                      // U = dinv*(X@Wc)
    agg_kernel<true, true><<<aggBlocks, 256, 0, stream>>>(
        Ybf, offs, esrc, dinv, Hbf, rvec, N);            // V = dinv*(A U), r
    aggmeanlv_kernel<<<aggBlocks, 256, 0, stream>>>(
        Hbf, offs, esrc, dinv, rvec, bc, b2c, noise,
        mean_out, lv_out, z_out, Zbf, N);                // mean/lv/z + zb

    // ---- decoder: out = A^2 z Wd + r*bd12 + bd2 ----
    agg64_kernel<true><<<aggBlocks, 256, 0, stream>>>(
        Zbf, offs, esrc, dinv, Ybf, N);                  // P = dinv*(A z)
    agg64_kernel<false><<<aggBlocks, 256, 0, stream>>>(
        Ybf, offs, esrc, dinv, Hbf, N);                  // Q = A^2 z
    matmul_out_kernel<<<gx, 256, 0, stream>>>(
        Hbf, Wd, rvec, bd12, b_d2, gout, N);             // out (fp32)
}